// Round 3
// baseline (1650.699 us; speedup 1.0000x reference)
//
#include <hip/hip_runtime.h>

// SiameseEdgeConvNet: 2-layer EdgeConv (max aggr) on two graphs, shared weights.
// N=50000, E=1.6e6, dims 32 -> 64 -> 64.
//
// Algebra (same as R2): msg = relu(xi@A + xj@B + b), A=W_lo-W_hi, B=W_hi.
//   u = x@A + b, v = x@B per node; ReLU monotone =>
//   out[d] = relu(u[d] + max_{e: dst=d} v[src_e]).
// R3 change: no CSR. segment_max via uint atomicMax on an order-isomorphic
//   key transform (works for NEGATIVE floats too):
//     key(f) = b<0 ? ~b : b|0x8000_0000   (b = float bits)
//   key==0 decodes to -NaN => impossible for real v => empty-row sentinel
//   (reproduces jax's isfinite->0 fixup with zero bookkeeping).
//   Read-then-atomic: stale reads are monotonically SMALLER => only extra
//   (harmless) atomics, never a missed max.
// PReLU input >= 0 (max of relus) -> identity -> skipped.

constexpr int HID = 64;

__device__ __forceinline__ unsigned int enc_key(float f) {
    unsigned int b = __float_as_uint(f);
    return (b & 0x80000000u) ? ~b : (b | 0x80000000u);
}
__device__ __forceinline__ float dec_key(unsigned int k) {
    unsigned int b = (k & 0x80000000u) ? (k ^ 0x80000000u) : ~k;
    return __uint_as_float(b);
}

struct GP {                 // one graph's pointer set
    const float* x;         // [N,32] layer-1 input
    const int*   src;       // [E]
    const int*   dst;       // [E]
    float*       u;         // [N,64]
    float*       v;         // [N,64]
    unsigned int* agg;      // [N,64] key space (memset 0 = empty)
    float*       out;       // [N,64] final output slot in d_out
};

// ---- layer-1 node GEMM: u = x@A + b, v = x@B (lane = out channel) ----
__global__ __launch_bounds__(256) void gemm_uv32_kernel(
    GP p0, GP p1, const float* __restrict__ W, const float* __restrict__ bias, int N)
{
    const GP p = blockIdx.y ? p1 : p0;
    const int lane = threadIdx.x & 63;
    const int wid  = (blockIdx.x * 256 + threadIdx.x) >> 6;
    const int nW   = (gridDim.x * 256) >> 6;

    float a_reg[32], b_reg[32];
    #pragma unroll
    for (int k = 0; k < 32; ++k) {
        float wlo = W[k * HID + lane];
        float whi = W[(32 + k) * HID + lane];
        a_reg[k] = wlo - whi;
        b_reg[k] = whi;
    }
    const float bv = bias[lane];

    for (int n = wid; n < N; n += nW) {
        const float xr = p.x[(size_t)n * 32 + (lane & 31)];
        float uu = bv, vv = 0.f;
        #pragma unroll
        for (int k = 0; k < 32; ++k) {
            const float xk = __shfl(xr, k);
            uu = fmaf(xk, a_reg[k], uu);
            vv = fmaf(xk, b_reg[k], vv);
        }
        p.u[(size_t)n * HID + lane] = uu;
        p.v[(size_t)n * HID + lane] = vv;
    }
}

// ---- edge phase: agg[d] = max(agg[d], key(v[s])), 16 threads/edge ----
__global__ __launch_bounds__(256) void edge_max_atomic_kernel(GP p0, GP p1, int E)
{
    const GP p = blockIdx.y ? p1 : p0;
    const int idx = blockIdx.x * 256 + threadIdx.x;
    const int e = idx >> 4;
    if (e >= E) return;
    const int sub = idx & 15;

    const int s = p.src[e];
    const int d = p.dst[e];
    const float4 vv = ((const float4*)p.v)[(size_t)s * 16 + sub];
    const uint4 cur = ((const uint4*)p.agg)[(size_t)d * 16 + sub];
    unsigned int* a = p.agg + (size_t)d * HID + sub * 4;

    unsigned int k;
    k = enc_key(vv.x); if (k > cur.x) atomicMax(a + 0, k);
    k = enc_key(vv.y); if (k > cur.y) atomicMax(a + 1, k);
    k = enc_key(vv.z); if (k > cur.z) atomicMax(a + 2, k);
    k = enc_key(vv.w); if (k > cur.w) atomicMax(a + 3, k);
}

// ---- layer-2 node GEMM with fused layer-1 decode:
//      h = (key==0) ? 0 : relu(u + dec(key));  u' = h@A2 + b2, v' = h@B2 ----
__global__ __launch_bounds__(256) void gemm_uv64_fused_kernel(
    GP p0, GP p1, const float* __restrict__ W, const float* __restrict__ bias, int N)
{
    const GP p = blockIdx.y ? p1 : p0;
    const int lane = threadIdx.x & 63;
    const int wid  = (blockIdx.x * 256 + threadIdx.x) >> 6;
    const int nW   = (gridDim.x * 256) >> 6;

    float a_reg[64], b_reg[64];
    #pragma unroll
    for (int k = 0; k < 64; ++k) {
        float wlo = W[k * HID + lane];
        float whi = W[(64 + k) * HID + lane];
        a_reg[k] = wlo - whi;
        b_reg[k] = whi;
    }
    const float bv = bias[lane];

    for (int n = wid; n < N; n += nW) {
        const size_t off = (size_t)n * HID + lane;
        const unsigned int kk = p.agg[off];
        const float uin = p.u[off];
        const float h = (kk == 0u) ? 0.f : fmaxf(uin + dec_key(kk), 0.f);
        float uu = bv, vv = 0.f;
        #pragma unroll
        for (int k = 0; k < 64; ++k) {
            const float hk = __shfl(h, k);
            uu = fmaf(hk, a_reg[k], uu);
            vv = fmaf(hk, b_reg[k], vv);
        }
        p.u[off] = uu;   // in-place: each thread read its own u/agg before write
        p.v[off] = vv;
    }
}

// ---- final decode: out = (key==0) ? 0 : relu(u + dec(key)) ----
__global__ __launch_bounds__(256) void decode_kernel(GP p0, GP p1, int N16)
{
    const GP p = blockIdx.y ? p1 : p0;
    const int idx = blockIdx.x * 256 + threadIdx.x;
    if (idx >= N16) return;
    const uint4 kk = ((const uint4*)p.agg)[idx];
    const float4 uu = ((const float4*)p.u)[idx];
    float4 r;
    r.x = kk.x ? fmaxf(uu.x + dec_key(kk.x), 0.f) : 0.f;
    r.y = kk.y ? fmaxf(uu.y + dec_key(kk.y), 0.f) : 0.f;
    r.z = kk.z ? fmaxf(uu.z + dec_key(kk.z), 0.f) : 0.f;
    r.w = kk.w ? fmaxf(uu.w + dec_key(kk.w), 0.f) : 0.f;
    ((float4*)p.out)[idx] = r;
}

// ---- orchestration ----
extern "C" void kernel_launch(void* const* d_in, const int* in_sizes, int n_in,
                              void* d_out, int out_size, void* d_ws, size_t ws_size,
                              hipStream_t stream) {
    const float* x1  = (const float*)d_in[0];
    const int*   ei1 = (const int*)d_in[1];   // [2,E]: src row then dst row
    const float* x2  = (const float*)d_in[2];
    const int*   ei2 = (const int*)d_in[3];
    const float* W1  = (const float*)d_in[4];
    const float* b1  = (const float*)d_in[5];
    // d_in[6] = prelu_a: unused (identity on >=0)
    const float* W2  = (const float*)d_in[7];
    const float* b2  = (const float*)d_in[8];

    const int N = in_sizes[0] / 32;
    const int E = in_sizes[1] / 2;
    float* out = (float*)d_out;

    const size_t rowB = (size_t)N * HID * sizeof(float);   // 12.8 MB
    const int gB = 1024;                                   // gemm blocks per graph
    const int eB = (16 * E + 255) / 256;                   // edge blocks per graph
    const int dB = (N * 16 + 255) / 256;                   // decode blocks per graph

    char* ws = (char*)d_ws;

    if (ws_size >= 6 * rowB) {
        // both graphs in flight: 7 dispatches total
        float* u0 = (float*)(ws + 0 * rowB);
        float* v0 = (float*)(ws + 1 * rowB);
        float* u1 = (float*)(ws + 2 * rowB);
        float* v1 = (float*)(ws + 3 * rowB);
        unsigned int* g0a = (unsigned int*)(ws + 4 * rowB);
        unsigned int* g1a = (unsigned int*)(ws + 5 * rowB);   // contiguous with g0a

        GP g0{x1, ei1, ei1 + E, u0, v0, g0a, out};
        GP g1{x2, ei2, ei2 + E, u1, v1, g1a, out + (size_t)N * HID};

        hipMemsetAsync(g0a, 0, 2 * rowB, stream);
        gemm_uv32_kernel<<<dim3(gB, 2), 256, 0, stream>>>(g0, g1, W1, b1, N);
        edge_max_atomic_kernel<<<dim3(eB, 2), 256, 0, stream>>>(g0, g1, E);
        gemm_uv64_fused_kernel<<<dim3(gB, 2), 256, 0, stream>>>(g0, g1, W2, b2, N);
        hipMemsetAsync(g0a, 0, 2 * rowB, stream);
        edge_max_atomic_kernel<<<dim3(eB, 2), 256, 0, stream>>>(g0, g1, E);
        decode_kernel<<<dim3(dB, 2), 256, 0, stream>>>(g0, g1, N * 16);
    } else {
        // sequential fallback: 3 row-buffers, 14 dispatches
        float* u = (float*)(ws + 0 * rowB);
        float* v = (float*)(ws + 1 * rowB);
        unsigned int* ag = (unsigned int*)(ws + 2 * rowB);
        for (int g = 0; g < 2; ++g) {
            GP gp{g ? x2 : x1, g ? ei2 : ei1, (g ? ei2 : ei1) + E,
                  u, v, ag, out + (size_t)g * N * HID};
            hipMemsetAsync(ag, 0, rowB, stream);
            gemm_uv32_kernel<<<dim3(gB, 1), 256, 0, stream>>>(gp, gp, W1, b1, N);
            edge_max_atomic_kernel<<<dim3(eB, 1), 256, 0, stream>>>(gp, gp, E);
            gemm_uv64_fused_kernel<<<dim3(gB, 1), 256, 0, stream>>>(gp, gp, W2, b2, N);
            hipMemsetAsync(ag, 0, rowB, stream);
            edge_max_atomic_kernel<<<dim3(eB, 1), 256, 0, stream>>>(gp, gp, E);
            decode_kernel<<<dim3(dB, 1), 256, 0, stream>>>(gp, gp, N * 16);
        }
    }
}

// Round 4
// 916.169 us; speedup vs baseline: 1.8017x; 1.8017x over previous
//
#include <hip/hip_runtime.h>
#include <cfloat>

// SiameseEdgeConvNet: 2-layer EdgeConv (max aggr) on two graphs, shared weights.
// N=50000, E=1.6e6, dims 32 -> 64 -> 64.
//
// Algebra: msg = relu([xi, xj-xi] @ W + b) = relu(xi@A + xj@B + b),
//   A=W_lo-W_hi, B=W_hi.  u = x@A + b, v = x@B per node; ReLU monotone =>
//   out[d] = relu(u[d] + max_{e: dst=d} v[src_e]);  empty segment -> 0
//   (matches jax isfinite->0 fixup).  PReLU input >= 0 -> identity -> skipped.
//
// R4: CSR-pull design (R3's atomicMax push cost 1.4 GB HBM/layer — reverted).
//   Both graphs batched per dispatch (gridDim.y=2); scan emits wp directly;
//   layer-1 h stored in d_out slot (reused buffer); 8 dispatches total.

constexpr int HID = 64;

struct G {                   // one graph's pointer set
    const float* x;          // [N,32] layer-1 input
    const int*   src;        // [E]
    const int*   dst;        // [E]
    int* counts;             // [N]
    int* row_ptr;            // [N+1]
    int* wp;                 // [N]
    int* srcs;               // [E] CSR-ordered source ids
    float* u;                // [N,64]
    float* v;                // [N,64]
    float* out;              // [N,64] — holds h after layer 1, final after layer 2
};

// ---------------- CSR build ----------------

__global__ __launch_bounds__(256) void count_kernel(G g0, G g1, int E) {
    const G g = blockIdx.y ? g1 : g0;
    const int i = blockIdx.x * 256 + threadIdx.x;
    if (i < E) atomicAdd(&g.counts[g.dst[i]], 1);
}

// one block per graph: counts[N] -> exclusive row_ptr[N+1], wp = copy
__global__ __launch_bounds__(1024) void scan_kernel(G g0, G g1, int N) {
    const G g = blockIdx.y ? g1 : g0;
    __shared__ int bufA[1024], bufB[1024];
    const int t = threadIdx.x;
    const int chunk = (N + 1023) / 1024;
    const int beg = t * chunk, end = min(N, beg + chunk);
    int s = 0;
    for (int i = beg; i < end; ++i) s += g.counts[i];
    bufA[t] = s;
    __syncthreads();
    int* in = bufA; int* out = bufB;
    for (int off = 1; off < 1024; off <<= 1) {
        out[t] = in[t] + (t >= off ? in[t - off] : 0);
        __syncthreads();
        int* tmp = in; in = out; out = tmp;
    }
    int run = (t == 0) ? 0 : in[t - 1];
    for (int i = beg; i < end; ++i) {
        g.row_ptr[i] = run;
        g.wp[i] = run;
        run += g.counts[i];
    }
    if (t == 0) g.row_ptr[N] = in[1023];
}

__global__ __launch_bounds__(256) void scatter_kernel(G g0, G g1, int E) {
    const G g = blockIdx.y ? g1 : g0;
    const int i = blockIdx.x * 256 + threadIdx.x;
    if (i < E) {
        int pos = atomicAdd(&g.wp[g.dst[i]], 1);
        g.srcs[pos] = g.src[i];
    }
}

// ---------------- node GEMMs: u = in@A + b, v = in@B ----------------
// lane = output channel; weight columns in registers; input row bcast via shfl.

__global__ __launch_bounds__(256) void gemm_uv32_kernel(
    G g0, G g1, const float* __restrict__ W, const float* __restrict__ bias, int N)
{
    const G g = blockIdx.y ? g1 : g0;
    const int lane = threadIdx.x & 63;
    const int wid  = (blockIdx.x * 256 + threadIdx.x) >> 6;
    const int nW   = (gridDim.x * 256) >> 6;

    float a_reg[32], b_reg[32];
    #pragma unroll
    for (int k = 0; k < 32; ++k) {
        float wlo = W[k * HID + lane];
        float whi = W[(32 + k) * HID + lane];
        a_reg[k] = wlo - whi;
        b_reg[k] = whi;
    }
    const float bv = bias[lane];

    for (int n = wid; n < N; n += nW) {
        const float xr = g.x[(size_t)n * 32 + (lane & 31)];
        float uu = bv, vv = 0.f;
        #pragma unroll
        for (int k = 0; k < 32; ++k) {
            const float xk = __shfl(xr, k);
            uu = fmaf(xk, a_reg[k], uu);
            vv = fmaf(xk, b_reg[k], vv);
        }
        g.u[(size_t)n * HID + lane] = uu;
        g.v[(size_t)n * HID + lane] = vv;
    }
}

// layer 2: input is g.out (the h written by layer-1 edge_max)
__global__ __launch_bounds__(256) void gemm_uv64_kernel(
    G g0, G g1, const float* __restrict__ W, const float* __restrict__ bias, int N)
{
    const G g = blockIdx.y ? g1 : g0;
    const int lane = threadIdx.x & 63;
    const int wid  = (blockIdx.x * 256 + threadIdx.x) >> 6;
    const int nW   = (gridDim.x * 256) >> 6;

    float a_reg[64], b_reg[64];
    #pragma unroll
    for (int k = 0; k < 64; ++k) {
        float wlo = W[k * HID + lane];
        float whi = W[(64 + k) * HID + lane];
        a_reg[k] = wlo - whi;
        b_reg[k] = whi;
    }
    const float bv = bias[lane];

    for (int n = wid; n < N; n += nW) {
        const float hr = g.out[(size_t)n * HID + lane];
        float uu = bv, vv = 0.f;
        #pragma unroll
        for (int k = 0; k < 64; ++k) {
            const float hk = __shfl(hr, k);
            uu = fmaf(hk, a_reg[k], uu);
            vv = fmaf(hk, b_reg[k], vv);
        }
        g.u[(size_t)n * HID + lane] = uu;
        g.v[(size_t)n * HID + lane] = vv;
    }
}

// ---------------- edge phase (pull): out[d] = relu(u[d] + max v[srcs]) ----------------
// 16 threads/node, float4/thread = 64 channels; register max; one row-write/node.

__global__ __launch_bounds__(256) void edge_max_kernel(G g0, G g1, int N)
{
    const G g = blockIdx.y ? g1 : g0;
    const int node = blockIdx.x * 16 + (threadIdx.x >> 4);
    const int sub  = threadIdx.x & 15;
    if (node >= N) return;

    const int beg = g.row_ptr[node], end = g.row_ptr[node + 1];
    const float4* __restrict__ v4 = (const float4*)g.v;

    float4 m = make_float4(-FLT_MAX, -FLT_MAX, -FLT_MAX, -FLT_MAX);
    int e = beg;
    for (; e + 3 < end; e += 4) {   // 4 independent gathers in flight
        const int s0 = g.srcs[e],     s1 = g.srcs[e + 1];
        const int s2 = g.srcs[e + 2], s3 = g.srcs[e + 3];
        const float4 a = v4[(size_t)s0 * 16 + sub];
        const float4 b = v4[(size_t)s1 * 16 + sub];
        const float4 c = v4[(size_t)s2 * 16 + sub];
        const float4 d = v4[(size_t)s3 * 16 + sub];
        m.x = fmaxf(fmaxf(fmaxf(a.x, b.x), fmaxf(c.x, d.x)), m.x);
        m.y = fmaxf(fmaxf(fmaxf(a.y, b.y), fmaxf(c.y, d.y)), m.y);
        m.z = fmaxf(fmaxf(fmaxf(a.z, b.z), fmaxf(c.z, d.z)), m.z);
        m.w = fmaxf(fmaxf(fmaxf(a.w, b.w), fmaxf(c.w, d.w)), m.w);
    }
    for (; e < end; ++e) {
        const float4 a = v4[(size_t)g.srcs[e] * 16 + sub];
        m.x = fmaxf(m.x, a.x); m.y = fmaxf(m.y, a.y);
        m.z = fmaxf(m.z, a.z); m.w = fmaxf(m.w, a.w);
    }

    float4 r;
    if (beg == end) {
        r = make_float4(0.f, 0.f, 0.f, 0.f);     // no in-edges: isfinite->0 path
    } else {
        const float4 uu = ((const float4*)g.u)[(size_t)node * 16 + sub];
        r.x = fmaxf(uu.x + m.x, 0.f);
        r.y = fmaxf(uu.y + m.y, 0.f);
        r.z = fmaxf(uu.z + m.z, 0.f);
        r.w = fmaxf(uu.w + m.w, 0.f);
    }
    ((float4*)g.out)[(size_t)node * 16 + sub] = r;
}

// ---------------- orchestration ----------------

extern "C" void kernel_launch(void* const* d_in, const int* in_sizes, int n_in,
                              void* d_out, int out_size, void* d_ws, size_t ws_size,
                              hipStream_t stream) {
    const float* x1  = (const float*)d_in[0];
    const int*   ei1 = (const int*)d_in[1];   // [2,E]: src row then dst row
    const float* x2  = (const float*)d_in[2];
    const int*   ei2 = (const int*)d_in[3];
    const float* W1  = (const float*)d_in[4];
    const float* b1  = (const float*)d_in[5];
    // d_in[6] = prelu_a: unused (identity on >=0)
    const float* W2  = (const float*)d_in[7];
    const float* b2  = (const float*)d_in[8];

    const int N = in_sizes[0] / 32;
    const int E = in_sizes[1] / 2;
    float* out = (float*)d_out;

    const size_t rowB  = (size_t)N * HID * sizeof(float);   // 12.8 MB
    const size_t srcsB = (size_t)E * sizeof(int);           // 6.4 MB
    const size_t nB    = (size_t)N * sizeof(int);
    const size_t npB   = ((size_t)(N + 4) * sizeof(int) + 15) & ~(size_t)15;

    const int eBlk = (E + 255) / 256;
    const int nBlk = (N + 15) / 16;
    const int gBlk = 1024;

    const size_t needBoth = 4 * rowB + 2 * srcsB + 2 * (nB + npB + nB) + 64;

    auto run = [&](G ga, G gb, int ny) {
        // counts for both graphs are contiguous: one memset covers ga+gb when ny==2
        hipMemsetAsync(ga.counts, 0, (size_t)ny * nB, stream);
        count_kernel  <<<dim3(eBlk, ny), 256,  0, stream>>>(ga, gb, E);
        scan_kernel   <<<dim3(1,    ny), 1024, 0, stream>>>(ga, gb, N);
        scatter_kernel<<<dim3(eBlk, ny), 256,  0, stream>>>(ga, gb, E);
        gemm_uv32_kernel<<<dim3(gBlk, ny), 256, 0, stream>>>(ga, gb, W1, b1, N);
        edge_max_kernel <<<dim3(nBlk, ny), 256, 0, stream>>>(ga, gb, N);
        gemm_uv64_kernel<<<dim3(gBlk, ny), 256, 0, stream>>>(ga, gb, W2, b2, N);
        edge_max_kernel <<<dim3(nBlk, ny), 256, 0, stream>>>(ga, gb, N);
    };

    char* ws = (char*)d_ws;
    if (ws_size >= needBoth) {
        float* u0 = (float*)(ws);            ws += rowB;
        float* v0 = (float*)(ws);            ws += rowB;
        float* u1 = (float*)(ws);            ws += rowB;
        float* v1 = (float*)(ws);            ws += rowB;
        int* srcs0 = (int*)(ws);             ws += srcsB;
        int* srcs1 = (int*)(ws);             ws += srcsB;
        int* counts0 = (int*)(ws);           ws += nB;
        int* counts1 = (int*)(ws);           ws += nB;   // contiguous with counts0
        int* rp0 = (int*)(ws);               ws += npB;
        int* rp1 = (int*)(ws);               ws += npB;
        int* wp0 = (int*)(ws);               ws += nB;
        int* wp1 = (int*)(ws);

        G g0{x1, ei1, ei1 + E, counts0, rp0, wp0, srcs0, u0, v0, out};
        G g1{x2, ei2, ei2 + E, counts1, rp1, wp1, srcs1, u1, v1, out + (size_t)N * HID};
        run(g0, g1, 2);
    } else {
        // sequential fallback: one graph's buffers only (~33 MB)
        float* u = (float*)(ws);             ws += rowB;
        float* v = (float*)(ws);             ws += rowB;
        int* srcs = (int*)(ws);              ws += srcsB;
        int* counts = (int*)(ws);            ws += nB;
        int* rp = (int*)(ws);                ws += npB;
        int* wp = (int*)(ws);

        for (int g = 0; g < 2; ++g) {
            const int* ei = g ? ei2 : ei1;
            G gp{g ? x2 : x1, ei, ei + E, counts, rp, wp, srcs,
                 u, v, out + (size_t)g * N * HID};
            run(gp, gp, 1);
        }
    }
}

// Round 5
// 584.855 us; speedup vs baseline: 2.8224x; 1.5665x over previous
//
#include <hip/hip_runtime.h>

// SiameseEdgeConvNet: 2-layer EdgeConv (max aggr) on two graphs, shared weights.
// N=50000, E=1.6e6, dims 32 -> 64 -> 64.
//
// Algebra: msg = relu([xi, xj-xi] @ W + b) = relu(xi@A + xj@B + b),
//   A=W_lo-W_hi, B=W_hi.  u = x@A + b, v = x@B per node; ReLU monotone =>
//   out[d] = relu(u[d] + max_{e: dst=d} v[src_e]);  empty segment -> 0
//   (matches jax isfinite->0 fixup).  PReLU input >= 0 -> identity -> skipped.
//
// R5: tile-binned PUSH. Edges binned by dst>>7 (391 buckets) as packed 4B
//   records (src<<7 | dst&127) with block-level reservation (coalesced-ish
//   writes; kills R4 scatter's 16x write amplification). Aggregation: one
//   block per 128-node tile, LDS agg[128][68] of order-isomorphic uint keys
//   (key(f) = b<0 ? ~b : b|0x80000000; key 0 = -NaN = empty sentinel),
//   LDS atomicMax per channel, one coalesced row-write per node. The N-sized
//   CSR (count/scan/scatter over 50000 nodes) no longer exists.

constexpr int HID  = 64;
constexpr int TILE = 128;          // nodes per bucket (dst >> 7)
constexpr int ASTR = 68;           // LDS row stride: +4 pad breaks bank aliasing
constexpr int MAXNB = 512;         // max buckets (N <= 65536)
constexpr int EPT  = 16;           // edges per thread in bin_kernel

__device__ __forceinline__ unsigned int enc_key(float f) {
    unsigned int b = __float_as_uint(f);
    return (b & 0x80000000u) ? ~b : (b | 0x80000000u);
}
__device__ __forceinline__ float dec_key(unsigned int k) {
    unsigned int b = (k & 0x80000000u) ? (k ^ 0x80000000u) : ~k;
    return __uint_as_float(b);
}

struct G {                    // one graph's pointer set
    const float* x;           // [N,32] layer-1 input
    const int*   src;         // [E]
    const int*   dst;         // [E]
    int* bcnt;                // [NB]   bucket counts
    int* bptr;                // [NB+1] bucket offsets
    int* wp;                  // [NB]   bucket write pointers
    unsigned int* bin;        // [E]    packed records, bucket-grouped
    float* u;                 // [N,64]
    float* v;                 // [N,64]
    float* out;               // [N,64] — h after layer 1, final after layer 2
};

// ---- bucket histogram (LDS-staged) ----
__global__ __launch_bounds__(256) void hist_kernel(G g0, G g1, int E, int NB) {
    const G g = blockIdx.y ? g1 : g0;
    __shared__ int h[MAXNB];
    for (int i = threadIdx.x; i < NB; i += 256) h[i] = 0;
    __syncthreads();
    int i = blockIdx.x * 256 + threadIdx.x;
    const int stride = gridDim.x * 256;
    for (; i < E; i += stride) atomicAdd(&h[g.dst[i] >> 7], 1);
    __syncthreads();
    for (int t = threadIdx.x; t < NB; t += 256) {
        const int c = h[t];
        if (c) atomicAdd(&g.bcnt[t], c);
    }
}

// ---- exclusive scan over NB buckets -> bptr, wp (one block per graph) ----
__global__ __launch_bounds__(1024) void scan_kernel(G g0, G g1, int NB) {
    const G g = blockIdx.y ? g1 : g0;
    __shared__ int bufA[1024], bufB[1024];
    const int t = threadIdx.x;
    const int chunk = (NB + 1023) / 1024;
    const int beg = t * chunk, end = min(NB, beg + chunk);
    int s = 0;
    for (int i = beg; i < end; ++i) s += g.bcnt[i];
    bufA[t] = s;
    __syncthreads();
    int* in = bufA; int* out = bufB;
    for (int off = 1; off < 1024; off <<= 1) {
        out[t] = in[t] + (t >= off ? in[t - off] : 0);
        __syncthreads();
        int* tmp = in; in = out; out = tmp;
    }
    int run = (t == 0) ? 0 : in[t - 1];
    for (int i = beg; i < end; ++i) {
        g.bptr[i] = run;
        g.wp[i]   = run;
        run += g.bcnt[i];
    }
    if (t == 0) g.bptr[NB] = in[1023];
}

// ---- bin: block-reserved bucket scatter of packed records ----
__global__ __launch_bounds__(256) void bin_kernel(G g0, G g1, int E, int NB) {
    const G g = blockIdx.y ? g1 : g0;
    __shared__ int lh[MAXNB];   // local hist, then local write offset
    __shared__ int lb[MAXNB];   // reserved base per bucket
    for (int i = threadIdx.x; i < NB; i += 256) lh[i] = 0;
    __syncthreads();

    const int base = blockIdx.x * 256 * EPT;
    unsigned int rec[EPT];
    int bb[EPT];
    #pragma unroll
    for (int k = 0; k < EPT; ++k) {
        const int i = base + k * 256 + threadIdx.x;   // coalesced stream
        if (i < E) {
            const int d = g.dst[i];
            const int s = g.src[i];
            rec[k] = ((unsigned int)s << 7) | (unsigned int)(d & 127);
            bb[k]  = d >> 7;
            atomicAdd(&lh[bb[k]], 1);
        } else bb[k] = -1;
    }
    __syncthreads();
    for (int t = threadIdx.x; t < NB; t += 256) {
        const int c = lh[t];
        lb[t] = c ? atomicAdd(&g.wp[t], c) : 0;
        lh[t] = 0;
    }
    __syncthreads();
    #pragma unroll
    for (int k = 0; k < EPT; ++k) {
        if (bb[k] >= 0) {
            const int off = atomicAdd(&lh[bb[k]], 1);
            g.bin[lb[bb[k]] + off] = rec[k];
        }
    }
}

// ---- node GEMMs: u = in@A + b, v = in@B (lane = out channel) ----
__global__ __launch_bounds__(256) void gemm_uv32_kernel(
    G g0, G g1, const float* __restrict__ W, const float* __restrict__ bias, int N)
{
    const G g = blockIdx.y ? g1 : g0;
    const int lane = threadIdx.x & 63;
    const int wid  = (blockIdx.x * 256 + threadIdx.x) >> 6;
    const int nW   = (gridDim.x * 256) >> 6;

    float a_reg[32], b_reg[32];
    #pragma unroll
    for (int k = 0; k < 32; ++k) {
        const float wlo = W[k * HID + lane];
        const float whi = W[(32 + k) * HID + lane];
        a_reg[k] = wlo - whi;
        b_reg[k] = whi;
    }
    const float bv = bias[lane];

    for (int n = wid; n < N; n += nW) {
        const float xr = g.x[(size_t)n * 32 + (lane & 31)];
        float uu = bv, vv = 0.f;
        #pragma unroll
        for (int k = 0; k < 32; ++k) {
            const float xk = __shfl(xr, k);
            uu = fmaf(xk, a_reg[k], uu);
            vv = fmaf(xk, b_reg[k], vv);
        }
        g.u[(size_t)n * HID + lane] = uu;
        g.v[(size_t)n * HID + lane] = vv;
    }
}

__global__ __launch_bounds__(256) void gemm_uv64_kernel(
    G g0, G g1, const float* __restrict__ W, const float* __restrict__ bias, int N)
{
    const G g = blockIdx.y ? g1 : g0;
    const int lane = threadIdx.x & 63;
    const int wid  = (blockIdx.x * 256 + threadIdx.x) >> 6;
    const int nW   = (gridDim.x * 256) >> 6;

    float a_reg[64], b_reg[64];
    #pragma unroll
    for (int k = 0; k < 64; ++k) {
        const float wlo = W[k * HID + lane];
        const float whi = W[(64 + k) * HID + lane];
        a_reg[k] = wlo - whi;
        b_reg[k] = whi;
    }
    const float bv = bias[lane];

    for (int n = wid; n < N; n += nW) {
        const float hr = g.out[(size_t)n * HID + lane];   // h from layer-1 agg
        float uu = bv, vv = 0.f;
        #pragma unroll
        for (int k = 0; k < 64; ++k) {
            const float hk = __shfl(hr, k);
            uu = fmaf(hk, a_reg[k], uu);
            vv = fmaf(hk, b_reg[k], vv);
        }
        g.u[(size_t)n * HID + lane] = uu;
        g.v[(size_t)n * HID + lane] = vv;
    }
}

// ---- aggregate: one block per 128-node tile, LDS atomicMax on keys ----
__global__ __launch_bounds__(256) void agg_kernel(G g0, G g1, int N) {
    const G g = blockIdx.y ? g1 : g0;
    __shared__ unsigned int agg[TILE * ASTR];   // 34816 B
    for (int i = threadIdx.x; i < TILE * ASTR; i += 256) agg[i] = 0u;
    __syncthreads();

    const int b   = blockIdx.x;
    const int beg = g.bptr[b], end = g.bptr[b + 1];
    const int grp = threadIdx.x >> 4;           // 16 groups of 16 threads
    const int sub = threadIdx.x & 15;
    const float4* __restrict__ v4 = (const float4*)g.v;

    int r = beg + grp;
    for (; r + 16 < end; r += 32) {             // 2 gathers in flight per group
        const unsigned int r0 = g.bin[r], r1 = g.bin[r + 16];
        const float4 a = v4[(size_t)(r0 >> 7) * 16 + sub];
        const float4 c = v4[(size_t)(r1 >> 7) * 16 + sub];
        unsigned int* rowA = &agg[(r0 & 127u) * ASTR + sub * 4];
        unsigned int* rowC = &agg[(r1 & 127u) * ASTR + sub * 4];
        atomicMax(rowA + 0, enc_key(a.x)); atomicMax(rowA + 1, enc_key(a.y));
        atomicMax(rowA + 2, enc_key(a.z)); atomicMax(rowA + 3, enc_key(a.w));
        atomicMax(rowC + 0, enc_key(c.x)); atomicMax(rowC + 1, enc_key(c.y));
        atomicMax(rowC + 2, enc_key(c.z)); atomicMax(rowC + 3, enc_key(c.w));
    }
    if (r < end) {
        const unsigned int r0 = g.bin[r];
        const float4 a = v4[(size_t)(r0 >> 7) * 16 + sub];
        unsigned int* rowA = &agg[(r0 & 127u) * ASTR + sub * 4];
        atomicMax(rowA + 0, enc_key(a.x)); atomicMax(rowA + 1, enc_key(a.y));
        atomicMax(rowA + 2, enc_key(a.z)); atomicMax(rowA + 3, enc_key(a.w));
    }
    __syncthreads();

    const int nodeBase = b * TILE;
    for (int i = threadIdx.x; i < TILE * HID; i += 256) {
        const int nl = i >> 6, ch = i & 63;
        const int node = nodeBase + nl;
        if (node < N) {
            const unsigned int k = agg[nl * ASTR + ch];
            float rlt = 0.f;                                  // empty -> 0
            if (k) rlt = fmaxf(g.u[(size_t)node * HID + ch] + dec_key(k), 0.f);
            g.out[(size_t)node * HID + ch] = rlt;             // coalesced
        }
    }
}

// ---------------- orchestration ----------------

extern "C" void kernel_launch(void* const* d_in, const int* in_sizes, int n_in,
                              void* d_out, int out_size, void* d_ws, size_t ws_size,
                              hipStream_t stream) {
    const float* x1  = (const float*)d_in[0];
    const int*   ei1 = (const int*)d_in[1];   // [2,E]: src row then dst row
    const float* x2  = (const float*)d_in[2];
    const int*   ei2 = (const int*)d_in[3];
    const float* W1  = (const float*)d_in[4];
    const float* b1  = (const float*)d_in[5];
    // d_in[6] = prelu_a: unused (identity on >=0)
    const float* W2  = (const float*)d_in[7];
    const float* b2  = (const float*)d_in[8];

    const int N  = in_sizes[0] / 32;
    const int E  = in_sizes[1] / 2;
    const int NB = (N + TILE - 1) / TILE;     // 391 for N=50000
    float* out = (float*)d_out;

    const size_t rowB = (size_t)N * HID * sizeof(float);           // 12.8 MB
    const size_t binB = ((size_t)E * sizeof(int) + 63) & ~(size_t)63;
    const size_t nbB  = ((size_t)(NB + 2) * sizeof(int) + 63) & ~(size_t)63;

    const int hBlk = 256;
    const int bBlk = (E + 256 * EPT - 1) / (256 * EPT);
    const int gBlk = 1024;

    auto run = [&](G ga, G gb, int ny) {
        // bcnt arrays contiguous across graphs: one memset when ny==2
        hipMemsetAsync(ga.bcnt, 0, (size_t)ny * nbB, stream);
        hist_kernel<<<dim3(hBlk, ny), 256, 0, stream>>>(ga, gb, E, NB);
        scan_kernel<<<dim3(1, ny), 1024, 0, stream>>>(ga, gb, NB);
        bin_kernel <<<dim3(bBlk, ny), 256, 0, stream>>>(ga, gb, E, NB);
        gemm_uv32_kernel<<<dim3(gBlk, ny), 256, 0, stream>>>(ga, gb, W1, b1, N);
        agg_kernel      <<<dim3(NB, ny), 256, 0, stream>>>(ga, gb, N);
        gemm_uv64_kernel<<<dim3(gBlk, ny), 256, 0, stream>>>(ga, gb, W2, b2, N);
        agg_kernel      <<<dim3(NB, ny), 256, 0, stream>>>(ga, gb, N);
    };

    char* ws = (char*)d_ws;
    const size_t needBoth = 4 * rowB + 2 * binB + 6 * nbB;

    if (ws_size >= needBoth) {
        float* u0 = (float*)ws;            ws += rowB;
        float* v0 = (float*)ws;            ws += rowB;
        float* u1 = (float*)ws;            ws += rowB;
        float* v1 = (float*)ws;            ws += rowB;
        unsigned int* bin0 = (unsigned int*)ws;  ws += binB;
        unsigned int* bin1 = (unsigned int*)ws;  ws += binB;
        int* bcnt0 = (int*)ws;             ws += nbB;
        int* bcnt1 = (int*)ws;             ws += nbB;   // contiguous with bcnt0
        int* bptr0 = (int*)ws;             ws += nbB;
        int* bptr1 = (int*)ws;             ws += nbB;
        int* wp0   = (int*)ws;             ws += nbB;
        int* wp1   = (int*)ws;

        G g0{x1, ei1, ei1 + E, bcnt0, bptr0, wp0, bin0, u0, v0, out};
        G g1{x2, ei2, ei2 + E, bcnt1, bptr1, wp1, bin1, u1, v1,
             out + (size_t)N * HID};
        run(g0, g1, 2);
    } else {
        // sequential fallback (~33 MB): one graph's buffers, reused
        float* u = (float*)ws;             ws += rowB;
        float* v = (float*)ws;             ws += rowB;
        unsigned int* bin = (unsigned int*)ws;   ws += binB;
        int* bcnt = (int*)ws;              ws += nbB;
        int* bptr = (int*)ws;              ws += nbB;
        int* wp   = (int*)ws;

        for (int g = 0; g < 2; ++g) {
            const int* ei = g ? ei2 : ei1;
            G gp{g ? x2 : x1, ei, ei + E, bcnt, bptr, wp, bin,
                 u, v, out + (size_t)g * N * HID};
            run(gp, gp, 1);
        }
    }
}

// Round 6
// 381.511 us; speedup vs baseline: 4.3267x; 1.5330x over previous
//
#include <hip/hip_runtime.h>
#include <hip/hip_fp16.h>

// SiameseEdgeConvNet: 2-layer EdgeConv (max aggr) on two graphs, shared weights.
// N=50000, E=1.6e6, dims 32 -> 64 -> 64.
//
// Algebra: msg = relu([xi, xj-xi] @ W + b) = relu(xi@A + xj@B + b),
//   A=W_lo-W_hi, B=W_hi.  u = x@A + b, v = x@B per node; ReLU monotone =>
//   out[d] = relu(u[d] + max_{e: dst=d} v[src_e]);  empty segment -> 0
//   (matches jax isfinite->0 fixup).  PReLU input >= 0 -> identity -> skipped.
//
// R6 (on R5's tile-binned push):
//   * v stored fp16 -> gather bytes halved (R5 FETCH 356 MB/dispatch).
//   * TILE 128->64 (1564 blocks, was 782 @ Occ 32%), ASTR 68->65: with 68 the
//     row base bank was 4r mod 32 => all 4 wave-groups always shared one
//     8-bank class = constant 8-way LDS conflicts (1.9e7 cyc measured). 65
//     gives base bank r mod 32.
//   * 4-deep gather unroll per 16-lane group (latency-bound regime).
//   Order-isomorphic key: key(f) = b<0 ? ~b : b|0x80000000; key 0 = -NaN =
//   empty sentinel. bin/hist/scan run once per graph, reused by both layers.

constexpr int HID   = 64;
constexpr int TILE  = 64;           // nodes per bucket (dst >> 6)
constexpr int ASTR  = 65;           // LDS row stride (uints): base bank = r mod 32
constexpr int MAXNB = 1024;         // max buckets (N <= 65536)
constexpr int EPT   = 16;           // edges per thread in bin_kernel

__device__ __forceinline__ unsigned int enc_key(float f) {
    unsigned int b = __float_as_uint(f);
    return (b & 0x80000000u) ? ~b : (b | 0x80000000u);
}
__device__ __forceinline__ float dec_key(unsigned int k) {
    unsigned int b = (k & 0x80000000u) ? (k ^ 0x80000000u) : ~k;
    return __uint_as_float(b);
}

struct G {                    // one graph's pointer set
    const float* x;           // [N,32] layer-1 input
    const int*   src;         // [E]
    const int*   dst;         // [E]
    int* bcnt;                // [NB]   bucket counts
    int* bptr;                // [NB+1] bucket offsets
    int* wp;                  // [NB]   bucket write pointers
    unsigned int* bin;        // [E]    packed records (src<<6 | dst&63)
    float*  u;                // [N,64] fp32
    __half* vh;               // [N,64] fp16
    float*  out;              // [N,64] — h after layer 1, final after layer 2
};

// ---- bucket histogram (LDS-staged) ----
__global__ __launch_bounds__(256) void hist_kernel(G g0, G g1, int E, int NB) {
    const G g = blockIdx.y ? g1 : g0;
    __shared__ int h[MAXNB];
    for (int i = threadIdx.x; i < NB; i += 256) h[i] = 0;
    __syncthreads();
    int i = blockIdx.x * 256 + threadIdx.x;
    const int stride = gridDim.x * 256;
    for (; i < E; i += stride) atomicAdd(&h[g.dst[i] >> 6], 1);
    __syncthreads();
    for (int t = threadIdx.x; t < NB; t += 256) {
        const int c = h[t];
        if (c) atomicAdd(&g.bcnt[t], c);
    }
}

// ---- exclusive scan over NB buckets -> bptr, wp (one block per graph) ----
__global__ __launch_bounds__(1024) void scan_kernel(G g0, G g1, int NB) {
    const G g = blockIdx.y ? g1 : g0;
    __shared__ int bufA[1024], bufB[1024];
    const int t = threadIdx.x;
    const int chunk = (NB + 1023) / 1024;
    const int beg = t * chunk, end = min(NB, beg + chunk);
    int s = 0;
    for (int i = beg; i < end; ++i) s += g.bcnt[i];
    bufA[t] = s;
    __syncthreads();
    int* in = bufA; int* out = bufB;
    for (int off = 1; off < 1024; off <<= 1) {
        out[t] = in[t] + (t >= off ? in[t - off] : 0);
        __syncthreads();
        int* tmp = in; in = out; out = tmp;
    }
    int run = (t == 0) ? 0 : in[t - 1];
    for (int i = beg; i < end; ++i) {
        g.bptr[i] = run;
        g.wp[i]   = run;
        run += g.bcnt[i];
    }
    if (t == 0) g.bptr[NB] = in[1023];
}

// ---- bin: block-reserved bucket scatter of packed records ----
__global__ __launch_bounds__(256) void bin_kernel(G g0, G g1, int E, int NB) {
    const G g = blockIdx.y ? g1 : g0;
    __shared__ int lh[MAXNB];   // local hist, then local write offset
    __shared__ int lb[MAXNB];   // reserved base per bucket
    for (int i = threadIdx.x; i < NB; i += 256) lh[i] = 0;
    __syncthreads();

    const int base = blockIdx.x * 256 * EPT;
    unsigned int rec[EPT];
    int bb[EPT];
    #pragma unroll
    for (int k = 0; k < EPT; ++k) {
        const int i = base + k * 256 + threadIdx.x;   // coalesced stream
        if (i < E) {
            const int d = g.dst[i];
            const int s = g.src[i];
            rec[k] = ((unsigned int)s << 6) | (unsigned int)(d & 63);
            bb[k]  = d >> 6;
            atomicAdd(&lh[bb[k]], 1);
        } else bb[k] = -1;
    }
    __syncthreads();
    for (int t = threadIdx.x; t < NB; t += 256) {
        const int c = lh[t];
        lb[t] = c ? atomicAdd(&g.wp[t], c) : 0;
        lh[t] = 0;
    }
    __syncthreads();
    #pragma unroll
    for (int k = 0; k < EPT; ++k) {
        if (bb[k] >= 0) {
            const int off = atomicAdd(&lh[bb[k]], 1);
            g.bin[lb[bb[k]] + off] = rec[k];
        }
    }
}

// ---- node GEMMs: u = in@A + b (fp32), v = in@B (fp16) ----
__global__ __launch_bounds__(256) void gemm_uv32_kernel(
    G g0, G g1, const float* __restrict__ W, const float* __restrict__ bias, int N)
{
    const G g = blockIdx.y ? g1 : g0;
    const int lane = threadIdx.x & 63;
    const int wid  = (blockIdx.x * 256 + threadIdx.x) >> 6;
    const int nW   = (gridDim.x * 256) >> 6;

    float a_reg[32], b_reg[32];
    #pragma unroll
    for (int k = 0; k < 32; ++k) {
        const float wlo = W[k * HID + lane];
        const float whi = W[(32 + k) * HID + lane];
        a_reg[k] = wlo - whi;
        b_reg[k] = whi;
    }
    const float bv = bias[lane];

    for (int n = wid; n < N; n += nW) {
        const float xr = g.x[(size_t)n * 32 + (lane & 31)];
        float uu = bv, vv = 0.f;
        #pragma unroll
        for (int k = 0; k < 32; ++k) {
            const float xk = __shfl(xr, k);
            uu = fmaf(xk, a_reg[k], uu);
            vv = fmaf(xk, b_reg[k], vv);
        }
        g.u [(size_t)n * HID + lane] = uu;
        g.vh[(size_t)n * HID + lane] = __float2half_rn(vv);
    }
}

__global__ __launch_bounds__(256) void gemm_uv64_kernel(
    G g0, G g1, const float* __restrict__ W, const float* __restrict__ bias, int N)
{
    const G g = blockIdx.y ? g1 : g0;
    const int lane = threadIdx.x & 63;
    const int wid  = (blockIdx.x * 256 + threadIdx.x) >> 6;
    const int nW   = (gridDim.x * 256) >> 6;

    float a_reg[64], b_reg[64];
    #pragma unroll
    for (int k = 0; k < 64; ++k) {
        const float wlo = W[k * HID + lane];
        const float whi = W[(64 + k) * HID + lane];
        a_reg[k] = wlo - whi;
        b_reg[k] = whi;
    }
    const float bv = bias[lane];

    for (int n = wid; n < N; n += nW) {
        const float hr = g.out[(size_t)n * HID + lane];   // h from layer-1 agg
        float uu = bv, vv = 0.f;
        #pragma unroll
        for (int k = 0; k < 64; ++k) {
            const float hk = __shfl(hr, k);
            uu = fmaf(hk, a_reg[k], uu);
            vv = fmaf(hk, b_reg[k], vv);
        }
        g.u [(size_t)n * HID + lane] = uu;
        g.vh[(size_t)n * HID + lane] = __float2half_rn(vv);
    }
}

// ---- aggregate: one block per 64-node tile, LDS atomicMax on keys ----
__global__ __launch_bounds__(256) void agg_kernel(G g0, G g1, int N) {
    const G g = blockIdx.y ? g1 : g0;
    __shared__ unsigned int agg[TILE * ASTR];   // 64*65*4 = 16640 B
    for (int i = threadIdx.x; i < TILE * ASTR; i += 256) agg[i] = 0u;
    __syncthreads();

    const int b   = blockIdx.x;
    const int beg = g.bptr[b], end = g.bptr[b + 1];
    const int grp = threadIdx.x >> 4;           // 16 groups of 16 lanes
    const int sub = threadIdx.x & 15;
    const uint2* __restrict__ v2 = (const uint2*)g.vh;   // 8 B = 4 fp16/lane

    #define PUSH(RAW, REC)                                                   \
    {                                                                        \
        const __half2 h0 = *reinterpret_cast<const __half2*>(&(RAW).x);      \
        const __half2 h1 = *reinterpret_cast<const __half2*>(&(RAW).y);      \
        const float2 f0 = __half22float2(h0);                                \
        const float2 f1 = __half22float2(h1);                                \
        unsigned int* row = &agg[((REC) & 63u) * ASTR + sub * 4];            \
        atomicMax(row + 0, enc_key(f0.x));                                   \
        atomicMax(row + 1, enc_key(f0.y));                                   \
        atomicMax(row + 2, enc_key(f1.x));                                   \
        atomicMax(row + 3, enc_key(f1.y));                                   \
    }

    int r = beg + grp;
    for (; r + 48 < end; r += 64) {             // 4 gather chains in flight
        const unsigned int q0 = g.bin[r],      q1 = g.bin[r + 16];
        const unsigned int q2 = g.bin[r + 32], q3 = g.bin[r + 48];
        const uint2 a0 = v2[(size_t)(q0 >> 6) * 16 + sub];
        const uint2 a1 = v2[(size_t)(q1 >> 6) * 16 + sub];
        const uint2 a2 = v2[(size_t)(q2 >> 6) * 16 + sub];
        const uint2 a3 = v2[(size_t)(q3 >> 6) * 16 + sub];
        PUSH(a0, q0) PUSH(a1, q1) PUSH(a2, q2) PUSH(a3, q3)
    }
    for (; r < end; r += 16) {
        const unsigned int q0 = g.bin[r];
        const uint2 a0 = v2[(size_t)(q0 >> 6) * 16 + sub];
        PUSH(a0, q0)
    }
    #undef PUSH
    __syncthreads();

    const int nodeBase = b * TILE;
    for (int i = threadIdx.x; i < TILE * HID; i += 256) {   // 16 iters, coalesced
        const int nl = i >> 6, ch = i & 63;
        const int node = nodeBase + nl;
        if (node < N) {
            const unsigned int k = agg[nl * ASTR + ch];
            float rlt = 0.f;                                  // empty -> 0
            if (k) rlt = fmaxf(g.u[(size_t)node * HID + ch] + dec_key(k), 0.f);
            g.out[(size_t)node * HID + ch] = rlt;
        }
    }
}

// ---------------- orchestration ----------------

extern "C" void kernel_launch(void* const* d_in, const int* in_sizes, int n_in,
                              void* d_out, int out_size, void* d_ws, size_t ws_size,
                              hipStream_t stream) {
    const float* x1  = (const float*)d_in[0];
    const int*   ei1 = (const int*)d_in[1];   // [2,E]: src row then dst row
    const float* x2  = (const float*)d_in[2];
    const int*   ei2 = (const int*)d_in[3];
    const float* W1  = (const float*)d_in[4];
    const float* b1  = (const float*)d_in[5];
    // d_in[6] = prelu_a: unused (identity on >=0)
    const float* W2  = (const float*)d_in[7];
    const float* b2  = (const float*)d_in[8];

    const int N  = in_sizes[0] / 32;
    const int E  = in_sizes[1] / 2;
    const int NB = (N + TILE - 1) / TILE;     // 782 for N=50000
    float* out = (float*)d_out;

    const size_t rowB = (size_t)N * HID * sizeof(float);            // 12.8 MB
    const size_t vhB  = ((size_t)N * HID * sizeof(__half) + 63) & ~(size_t)63;
    const size_t binB = ((size_t)E * sizeof(int) + 63) & ~(size_t)63;
    const size_t nbB  = ((size_t)(NB + 2) * sizeof(int) + 63) & ~(size_t)63;

    const int hBlk = 256;
    const int bBlk = (E + 256 * EPT - 1) / (256 * EPT);
    const int gBlk = 1024;

    auto run = [&](G ga, G gb, int ny) {
        // bcnt arrays contiguous across graphs: one memset when ny==2
        hipMemsetAsync(ga.bcnt, 0, (size_t)ny * nbB, stream);
        hist_kernel<<<dim3(hBlk, ny), 256, 0, stream>>>(ga, gb, E, NB);
        scan_kernel<<<dim3(1, ny), 1024, 0, stream>>>(ga, gb, NB);
        bin_kernel <<<dim3(bBlk, ny), 256, 0, stream>>>(ga, gb, E, NB);
        gemm_uv32_kernel<<<dim3(gBlk, ny), 256, 0, stream>>>(ga, gb, W1, b1, N);
        agg_kernel      <<<dim3(NB,   ny), 256, 0, stream>>>(ga, gb, N);
        gemm_uv64_kernel<<<dim3(gBlk, ny), 256, 0, stream>>>(ga, gb, W2, b2, N);
        agg_kernel      <<<dim3(NB,   ny), 256, 0, stream>>>(ga, gb, N);
    };

    char* ws = (char*)d_ws;
    const size_t needBoth = 2 * rowB + 2 * vhB + 2 * binB + 6 * nbB;

    if (ws_size >= needBoth) {
        float* u0 = (float*)ws;                  ws += rowB;
        float* u1 = (float*)ws;                  ws += rowB;
        unsigned int* bin0 = (unsigned int*)ws;  ws += binB;
        unsigned int* bin1 = (unsigned int*)ws;  ws += binB;
        __half* vh0 = (__half*)ws;               ws += vhB;
        __half* vh1 = (__half*)ws;               ws += vhB;
        int* bcnt0 = (int*)ws;                   ws += nbB;
        int* bcnt1 = (int*)ws;                   ws += nbB;   // contiguous with bcnt0
        int* bptr0 = (int*)ws;                   ws += nbB;
        int* bptr1 = (int*)ws;                   ws += nbB;
        int* wp0   = (int*)ws;                   ws += nbB;
        int* wp1   = (int*)ws;

        G g0{x1, ei1, ei1 + E, bcnt0, bptr0, wp0, bin0, u0, vh0, out};
        G g1{x2, ei2, ei2 + E, bcnt1, bptr1, wp1, bin1, u1, vh1,
             out + (size_t)N * HID};
        run(g0, g1, 2);
    } else {
        // sequential fallback (~26 MB): one graph's buffers, reused
        float* u = (float*)ws;                   ws += rowB;
        unsigned int* bin = (unsigned int*)ws;   ws += binB;
        __half* vh = (__half*)ws;                ws += vhB;
        int* bcnt = (int*)ws;                    ws += nbB;
        int* bptr = (int*)ws;                    ws += nbB;
        int* wp   = (int*)ws;

        for (int g = 0; g < 2; ++g) {
            const int* ei = g ? ei2 : ei1;
            G gp{g ? x2 : x1, ei, ei + E, bcnt, bptr, wp, bin,
                 u, vh, out + (size_t)g * N * HID};
            run(gp, gp, 1);
        }
    }
}